// Round 4
// baseline (331.421 us; speedup 1.0000x reference)
//
#include <hip/hip_runtime.h>

// EdgeSageLayer on MI355X — round 11.
// agg[n] = (sum_{e:dst=n} concat(x[src_e], ea_e)) @ msg_w / deg + msg_b*(deg>0)
// R10 postmortem: total unchanged (274) -> agg + finalize_v3 == agg_fused
// (~90us). Two structural latency bugs found by arithmetic:
// (1) aggregate grid = 25000 waves for 25000 pairs -> each wave runs ONE
//     pair; the serial chain cnt->bucket->shfl->3 sequential gather rounds
//     is fully exposed (dynamic-bound loop never unrolled by compiler).
// (2) finalize_v3 has no prefetch: 6 loads (~600cyc) then 640 dependent
//     VALU ops per pair at 2 waves/SIMD -> latency adds ~50% over floor.
// R11: aggregate1_k = 1 node/wave (50000 waves, 2x latency hiding, perfect
// degree balance), bucket row loaded unconditionally+immediately (kills the
// cnt->bucket serialization), gather FULLY UNROLLED over CAP=48 into 18
// load slots with wave-uniform chunk guards -> every live load issues
// before any accumulate. finalize_v4_k = 1 node/iter with software
// prefetch of next node's rows+cnt under the current node's 320 FMAs,
// 4 accumulators/loop for FMA ILP.

constexpr int N_NODES  = 50000;
constexpr int N_EDGES  = 800000;
constexpr int IN_DIM   = 64;
constexpr int EDGE_DIM = 32;
constexpr int OUT_DIM  = 64;
constexpr int CAP      = 48;      // bucket capacity; Poisson(16) max deg ~40
constexpr int OVF_CAP  = 65536;   // overflow list capacity (deg>CAP tails)

using vf4 = __attribute__((ext_vector_type(4))) float;
using vi2 = __attribute__((ext_vector_type(2))) int;

__device__ __forceinline__ float rl(float v, int srclane) {
    return __int_as_float(__builtin_amdgcn_readlane(__float_as_int(v), srclane));
}

// ---------------------------------------------------------------------------
// K1: single-pass bucket build. pos = atomicAdd(cnt[dst]); write (e,src).
// Rare pos>=CAP goes to the overflow list.
// ---------------------------------------------------------------------------
__device__ __forceinline__ void place_one(int dst, int e, int src,
                                          int* cnt, int2* buckets,
                                          int4* ovf, int* ovf_cur) {
    const int pos = atomicAdd(&cnt[dst], 1);
    if (pos < CAP) {
        buckets[(size_t)dst * CAP + pos] = make_int2(e, src);
    } else {
        const int o = atomicAdd(ovf_cur, 1);
        if (o < OVF_CAP) ovf[o] = make_int4(dst, e, src, 0);
    }
}

__global__ __launch_bounds__(256) void place_bucket_k(
    const int* __restrict__ ei, int* cnt, int2* __restrict__ buckets,
    int4* __restrict__ ovf, int* ovf_cur)
{
    const int t = blockIdx.x * 256 + threadIdx.x;
    if (t * 4 + 3 < N_EDGES) {
        const int4 d4 = ((const int4*)(ei + N_EDGES))[t];
        const int4 s4 = ((const int4*)ei)[t];
        place_one(d4.x, 4 * t + 0, s4.x, cnt, buckets, ovf, ovf_cur);
        place_one(d4.y, 4 * t + 1, s4.y, cnt, buckets, ovf, ovf_cur);
        place_one(d4.z, 4 * t + 2, s4.z, cnt, buckets, ovf, ovf_cur);
        place_one(d4.w, 4 * t + 3, s4.w, cnt, buckets, ovf, ovf_cur);
    } else {
        for (int e = t * 4; e < min(t * 4 + 4, N_EDGES); ++e)
            place_one(ei[N_EDGES + e], e, ei[e], cnt, buckets, ovf, ovf_cur);
    }
}

// ---------------------------------------------------------------------------
// K2 (R11): gather-reduce, 1 node/wave, fully-unrolled 48-edge gather.
// x rows: float4 x 16 lanes (4 edges/instr, 12 slots); ea: float4 x 8 lanes
// (8 edges/instr, 6 slots). Bucket row loaded unconditionally (masks only at
// use); chunk guards c>16 / c>32 are wave-uniform s_cbranch. All live loads
// issue before any accumulate. shfl_xor reduce; zero stores for deg==0.
// ---------------------------------------------------------------------------
__global__ __launch_bounds__(256) void aggregate1_k(
    const float* __restrict__ x, const float* __restrict__ ea,
    const int2* __restrict__ buckets, const int* __restrict__ cnt,
    const int4* __restrict__ ovf, const int* __restrict__ ovf_cur,
    float* __restrict__ sum_x, float* __restrict__ sum_ea)
{
    const int lane = threadIdx.x & 63;
    const int wave = (blockIdx.x * blockDim.x + threadIdx.x) >> 6;
    if (wave >= N_NODES) return;
    const int n = __builtin_amdgcn_readfirstlane(wave);

    // bucket row: issue immediately, independent of cnt (always in-bounds;
    // entries beyond cnt are garbage but masked at every use).
    const vi2 p = __builtin_nontemporal_load(
        (const vi2*)buckets + (size_t)n * CAP + lane);
    const int cF = __builtin_amdgcn_readfirstlane(cnt[n]);
    const int c  = min(cF, CAP);
    const int e0 = p.x, s0 = p.y;

    const int grpx = lane >> 4, colx = lane & 15;  // x: 4 edges/instr
    const int grpe = lane >> 3, cole = lane & 7;   // ea: 8 edges/instr

    vf4 xt[12], et[6];
#pragma unroll
    for (int i = 0; i < 12; ++i) xt[i] = (vf4){0, 0, 0, 0};
#pragma unroll
    for (int i = 0; i < 6; ++i) et[i] = (vf4){0, 0, 0, 0};

    // chunk 0: edges 0..15 (always)
#pragma unroll
    for (int i = 0; i < 4; ++i) {
        const int jj = 4 * i + grpx;
        const int s  = __shfl(s0, jj);
        if (jj < c) xt[i] = ((const vf4*)(x + (size_t)s * IN_DIM))[colx];
    }
#pragma unroll
    for (int i = 0; i < 2; ++i) {
        const int jj = 8 * i + grpe;
        const int e  = __shfl(e0, jj);
        if (jj < c) et[i] = __builtin_nontemporal_load(
            (const vf4*)(ea + (size_t)e * EDGE_DIM) + cole);
    }
    // chunk 1: edges 16..31
    if (c > 16) {
#pragma unroll
        for (int i = 4; i < 8; ++i) {
            const int jj = 4 * i + grpx;
            const int s  = __shfl(s0, jj);
            if (jj < c) xt[i] = ((const vf4*)(x + (size_t)s * IN_DIM))[colx];
        }
#pragma unroll
        for (int i = 2; i < 4; ++i) {
            const int jj = 8 * i + grpe;
            const int e  = __shfl(e0, jj);
            if (jj < c) et[i] = __builtin_nontemporal_load(
                (const vf4*)(ea + (size_t)e * EDGE_DIM) + cole);
        }
    }
    // chunk 2: edges 32..47
    if (c > 32) {
#pragma unroll
        for (int i = 8; i < 12; ++i) {
            const int jj = 4 * i + grpx;
            const int s  = __shfl(s0, jj);
            if (jj < c) xt[i] = ((const vf4*)(x + (size_t)s * IN_DIM))[colx];
        }
#pragma unroll
        for (int i = 4; i < 6; ++i) {
            const int jj = 8 * i + grpe;
            const int e  = __shfl(e0, jj);
            if (jj < c) et[i] = __builtin_nontemporal_load(
                (const vf4*)(ea + (size_t)e * EDGE_DIM) + cole);
        }
    }

    // accumulate (balanced trees; first use forces the vmcnt waits)
    vf4 ax = ((xt[0] + xt[1]) + (xt[2] + xt[3])) +
             ((xt[4] + xt[5]) + (xt[6] + xt[7])) +
             ((xt[8] + xt[9]) + (xt[10] + xt[11]));
    vf4 ae = ((et[0] + et[1]) + (et[2] + et[3])) + (et[4] + et[5]);

    // rare: overflow entries (deg > CAP). Group 0 accumulates pre-reduce.
    if (cF > CAP) {
        const int novf = min(__builtin_amdgcn_readfirstlane(*ovf_cur), OVF_CAP);
        for (int i = 0; i < novf; ++i) {
            const int4 v = ovf[i];
            if (v.x == n) {
                if (grpx == 0)
                    ax += ((const vf4*)(x + (size_t)v.z * IN_DIM))[colx];
                if (grpe == 0)
                    ae += ((const vf4*)(ea + (size_t)v.y * EDGE_DIM))[cole];
            }
        }
    }

#pragma unroll
    for (int mask = 16; mask < 64; mask <<= 1) {
        ax.x += __shfl_xor(ax.x, mask); ax.y += __shfl_xor(ax.y, mask);
        ax.z += __shfl_xor(ax.z, mask); ax.w += __shfl_xor(ax.w, mask);
    }
#pragma unroll
    for (int mask = 8; mask < 64; mask <<= 1) {
        ae.x += __shfl_xor(ae.x, mask); ae.y += __shfl_xor(ae.y, mask);
        ae.z += __shfl_xor(ae.z, mask); ae.w += __shfl_xor(ae.w, mask);
    }

    if (lane < 16) ((vf4*)(sum_x + (size_t)n * IN_DIM))[lane] = ax;
    if (lane < 8)  ((vf4*)(sum_ea + (size_t)n * EDGE_DIM))[lane] = ae;
}

// ---------------------------------------------------------------------------
// K3 (R11): finalize_v4. Weights VGPR-resident (column-per-lane, 160).
// 1 node/iter; NEXT node's 3 rows + cnt prefetched under the current node's
// 320 FMAs (640 VALU cyc covers ~600 cyc load latency). readlane broadcast
// (VALU pipe, zero LDS). 4 accumulators/loop for FMA ILP. 2 waves/SIMD.
// sum_x_in aliases out; each row read then written by exactly one wave, and
// prefetch loads precede the store in program order.
// ---------------------------------------------------------------------------
__device__ __forceinline__ void fin_load_node(
    const float* x, const float* sum_x_in, const float* sum_ea,
    const int* cnt, int n, int lane,
    vf4& r1, vf4& r2, vf4& r3, int& d)
{
    r1 = (vf4){0, 0, 0, 0}; r2 = (vf4){0, 0, 0, 0}; r3 = (vf4){0, 0, 0, 0};
    if (lane < 16) {
        r1 = ((const vf4*)(sum_x_in + (size_t)n * IN_DIM))[lane];
        r3 = ((const vf4*)(x        + (size_t)n * IN_DIM))[lane];
    }
    if (lane < 8) r2 = ((const vf4*)(sum_ea + (size_t)n * EDGE_DIM))[lane];
    d = cnt[n];
}

__global__ __launch_bounds__(256, 2) void finalize_v4_k(
    const float* __restrict__ x, const float* sum_x_in,
    const float* __restrict__ sum_ea, const int* __restrict__ cnt,
    const float* __restrict__ msg_w, const float* __restrict__ msg_b,
    const float* __restrict__ self_w, const float* __restrict__ self_b,
    float* out)
{
    const int lane = threadIdx.x & 63;               // output column c
    const int wid  = blockIdx.x * 4 + (threadIdx.x >> 6);
    const int nw   = gridDim.x * 4;

    float wm[96];   // msg_w column `lane`
    float wsf[64];  // self_w column `lane`
#pragma unroll
    for (int k = 0; k < 96; ++k) wm[k] = msg_w[k * OUT_DIM + lane];
#pragma unroll
    for (int k = 0; k < 64; ++k) wsf[k] = self_w[k * OUT_DIM + lane];
    const float mb = msg_b[lane];
    const float sb = self_b[lane];

    int n = wid;
    if (n >= N_NODES) return;

    vf4 r1, r2, r3; int d;
    fin_load_node(x, sum_x_in, sum_ea, cnt,
                  __builtin_amdgcn_readfirstlane(n), lane, r1, r2, r3, d);

    while (true) {
        const int n1 = n + nw;
        vf4 q1 = {0,0,0,0}, q2 = {0,0,0,0}, q3 = {0,0,0,0}; int d1 = 0;
        if (n1 < N_NODES)
            fin_load_node(x, sum_x_in, sum_ea, cnt,
                          __builtin_amdgcn_readfirstlane(n1), lane,
                          q1, q2, q3, d1);

        // compute node n (prefetch above is in flight during these FMAs)
        float am0 = 0.f, am1 = 0.f, am2 = 0.f, am3 = 0.f;
        float as0 = 0.f, as1 = 0.f, as2 = 0.f, as3 = 0.f;
#pragma unroll
        for (int q = 0; q < 16; ++q) {
            am0 = fmaf(rl(r1[0], q), wm[4 * q + 0], am0);
            am1 = fmaf(rl(r1[1], q), wm[4 * q + 1], am1);
            am2 = fmaf(rl(r1[2], q), wm[4 * q + 2], am2);
            am3 = fmaf(rl(r1[3], q), wm[4 * q + 3], am3);
        }
#pragma unroll
        for (int q = 0; q < 8; ++q) {
            am0 = fmaf(rl(r2[0], q), wm[64 + 4 * q + 0], am0);
            am1 = fmaf(rl(r2[1], q), wm[64 + 4 * q + 1], am1);
            am2 = fmaf(rl(r2[2], q), wm[64 + 4 * q + 2], am2);
            am3 = fmaf(rl(r2[3], q), wm[64 + 4 * q + 3], am3);
        }
#pragma unroll
        for (int q = 0; q < 16; ++q) {
            as0 = fmaf(rl(r3[0], q), wsf[4 * q + 0], as0);
            as1 = fmaf(rl(r3[1], q), wsf[4 * q + 1], as1);
            as2 = fmaf(rl(r3[2], q), wsf[4 * q + 2], as2);
            as3 = fmaf(rl(r3[3], q), wsf[4 * q + 3], as3);
        }

        const float inv  = 1.0f / (float)max(d, 1);
        const float bsel = (d > 0) ? 1.0f : 0.0f;
        out[(size_t)n * OUT_DIM + lane] =
            ((as0 + as1) + (as2 + as3)) + sb +
            ((am0 + am1) + (am2 + am3)) * inv + mb * bsel;

        if (n1 >= N_NODES) break;
        n = n1; r1 = q1; r2 = q2; r3 = q3; d = d1;
    }
}

// ---------------------------------------------------------------------------
// Tier-3 fallback: atomic scatter (needs only ~6.6 MB ws).
// ---------------------------------------------------------------------------
__global__ __launch_bounds__(768) void scatter_fb_k(
    const float* __restrict__ x, const int* __restrict__ ei,
    const float* __restrict__ ea, float* sum_x, float* sum_ea, int* deg)
{
    const int t  = threadIdx.x;
    const int el = t / 96;
    const int k  = t - el * 96;
    const int e  = blockIdx.x * 8 + el;
    if (e >= N_EDGES) return;
    const int dst = ei[N_EDGES + e];
    if (k < IN_DIM) {
        const int src = ei[e];
        atomicAdd(&sum_x[dst * IN_DIM + k], x[src * IN_DIM + k]);
        if (k == 0) atomicAdd(&deg[dst], 1);
    } else {
        const int kk = k - IN_DIM;
        atomicAdd(&sum_ea[dst * EDGE_DIM + kk], ea[e * EDGE_DIM + kk]);
    }
}

// ---------------------------------------------------------------------------
extern "C" void kernel_launch(void* const* d_in, const int* in_sizes, int n_in,
                              void* d_out, int out_size, void* d_ws, size_t ws_size,
                              hipStream_t stream) {
    const float* x      = (const float*)d_in[0];
    const int*   ei     = (const int*)d_in[1];   // [2][E]
    const float* ea     = (const float*)d_in[2];
    const float* msg_w  = (const float*)d_in[3];
    const float* msg_b  = (const float*)d_in[4];
    const float* self_w = (const float*)d_in[5];
    const float* self_b = (const float*)d_in[6];

    float* out = (float*)d_out;  // doubles as sum_x accumulator

    // ws layout (ints unless noted):
    //   cnt[50000] | ovf_cur[1] | pad to 16 | buckets[50000*CAP int2]
    //   | ovf[OVF_CAP int4] | sum_ea[1.6M float]
    int*   cnt     = (int*)d_ws;
    int*   ovf_cur = cnt + N_NODES;
    int2*  buckets = (int2*)(cnt + N_NODES + 16);
    int4*  ovf     = (int4*)(buckets + (size_t)N_NODES * CAP);
    float* sum_ea  = (float*)(ovf + OVF_CAP);
    const size_t need_bucket =
        ((size_t)N_NODES + 16 + 2 * (size_t)N_NODES * CAP + 4 * (size_t)OVF_CAP +
         (size_t)N_NODES * EDGE_DIM) * sizeof(int);

    if (ws_size >= need_bucket) {
        hipMemsetAsync(cnt, 0, (N_NODES + 16) * sizeof(int), stream);
        place_bucket_k<<<(N_EDGES / 4 + 255) / 256, 256, 0, stream>>>(
            ei, cnt, buckets, ovf, ovf_cur);
        aggregate1_k<<<(N_NODES + 3) / 4, 256, 0, stream>>>(
            x, ea, buckets, cnt, ovf, ovf_cur, out, sum_ea);
        finalize_v4_k<<<512, 256, 0, stream>>>(
            x, out, sum_ea, cnt, msg_w, msg_b, self_w, self_b, out);
    } else {
        // Fallback: fp32 atomic scatter (R1 path) + finalize_v4
        float* fb_sum_ea = (float*)d_ws;
        int*   deg       = (int*)(fb_sum_ea + (size_t)N_NODES * EDGE_DIM);
        hipMemsetAsync(d_out, 0, (size_t)N_NODES * OUT_DIM * sizeof(float), stream);
        hipMemsetAsync(d_ws, 0, (size_t)N_NODES * (EDGE_DIM + 1) * sizeof(float), stream);
        scatter_fb_k<<<(N_EDGES + 7) / 8, 768, 0, stream>>>(
            x, ei, ea, out, fb_sum_ea, deg);
        finalize_v4_k<<<512, 256, 0, stream>>>(
            x, out, fb_sum_ea, deg, msg_w, msg_b, self_w, self_b, out);
    }
}

// Round 5
// 318.479 us; speedup vs baseline: 1.0406x; 1.0406x over previous
//
#include <hip/hip_runtime.h>

// EdgeSageLayer on MI355X — round 12.
// agg[n] = (sum_{e:dst=n} concat(x[src_e], ea_e)) @ msg_w / deg + msg_b*(deg>0)
// R11 postmortem: 1-node/wave aggregate REGRESSED 50->108us (occupancy 67->18%):
// per-wave in-flight loads (12 -> ~6) is the controlling variable, not wave
// count; short-lived 12500-WG kernels starve residency. finalize_v4 prefetch
// didn't help (39us): readlane scheme is ISSUE-bound (320 VALU/node, 26us floor).
// R12: aggregate reverts byte-for-byte to the proven R8 form (~50us).
// finalize_v5 transposes the parallelization: lane = NODE (64 nodes/wave),
// weight W[k][c] is wave-uniform -> SGPR operand folded into v_fmac (zero
// broadcasts, zero LDS) -> 160 FMA/node, 6.5us chip VALU floor. c-dim split
// in half per wave (acc[32], 1564 waves -> every CU busy). Per-lane row loads
// are L1-amortized (4 vf4 per 64B line). sum_x moves out->ws so the two
// c-half waves of a node never race the out buffer.

constexpr int N_NODES  = 50000;
constexpr int N_EDGES  = 800000;
constexpr int IN_DIM   = 64;
constexpr int EDGE_DIM = 32;
constexpr int OUT_DIM  = 64;
constexpr int CAP      = 48;      // bucket capacity; Poisson(16) max deg ~40
constexpr int OVF_CAP  = 65536;   // overflow list capacity (deg>CAP tails)

using vf4 = __attribute__((ext_vector_type(4))) float;
using vi2 = __attribute__((ext_vector_type(2))) int;

// ---------------------------------------------------------------------------
// K1: single-pass bucket build. pos = atomicAdd(cnt[dst]); write (e,src).
// Rare pos>=CAP goes to the overflow list.
// ---------------------------------------------------------------------------
__device__ __forceinline__ void place_one(int dst, int e, int src,
                                          int* cnt, int2* buckets,
                                          int4* ovf, int* ovf_cur) {
    const int pos = atomicAdd(&cnt[dst], 1);
    if (pos < CAP) {
        buckets[(size_t)dst * CAP + pos] = make_int2(e, src);
    } else {
        const int o = atomicAdd(ovf_cur, 1);
        if (o < OVF_CAP) ovf[o] = make_int4(dst, e, src, 0);
    }
}

__global__ __launch_bounds__(256) void place_bucket_k(
    const int* __restrict__ ei, int* cnt, int2* __restrict__ buckets,
    int4* __restrict__ ovf, int* ovf_cur)
{
    const int t = blockIdx.x * 256 + threadIdx.x;
    if (t * 4 + 3 < N_EDGES) {
        const int4 d4 = ((const int4*)(ei + N_EDGES))[t];
        const int4 s4 = ((const int4*)ei)[t];
        place_one(d4.x, 4 * t + 0, s4.x, cnt, buckets, ovf, ovf_cur);
        place_one(d4.y, 4 * t + 1, s4.y, cnt, buckets, ovf, ovf_cur);
        place_one(d4.z, 4 * t + 2, s4.z, cnt, buckets, ovf, ovf_cur);
        place_one(d4.w, 4 * t + 3, s4.w, cnt, buckets, ovf, ovf_cur);
    } else {
        for (int e = t * 4; e < min(t * 4 + 4, N_EDGES); ++e)
            place_one(ei[N_EDGES + e], e, ei[e], cnt, buckets, ovf, ovf_cur);
    }
}

// ---------------------------------------------------------------------------
// K2 (R8 proven form, unchanged): gather-reduce, 2 nodes/wave, 16 edges/iter,
// 12 gathers issued into zero-init masked temps before any accumulate.
// ---------------------------------------------------------------------------
__global__ __launch_bounds__(256) void aggregate_bucket_k(
    const float* __restrict__ x, const float* __restrict__ ea,
    const int2* __restrict__ buckets, const int* __restrict__ cnt,
    const int4* __restrict__ ovf, const int* __restrict__ ovf_cur,
    float* __restrict__ sum_x, float* __restrict__ sum_ea)
{
    const int lane   = threadIdx.x & 63;
    const int wave   = (blockIdx.x * blockDim.x + threadIdx.x) >> 6;
    const int nwaves = (gridDim.x * blockDim.x) >> 6;

    const int grpx = lane >> 4, colx = lane & 15;  // x: 4 edges/step
    const int grpe = lane >> 3, cole = lane & 7;   // ea: 8 edges/step

    for (int n0 = wave * 2; n0 < N_NODES; n0 += nwaves * 2) {
        const int  nA   = __builtin_amdgcn_readfirstlane(n0);
        const bool hasB = (n0 + 1 < N_NODES);
        const int  nB   = nA + 1;

        const int cFA = __builtin_amdgcn_readfirstlane(cnt[nA]);
        const int cFB = hasB ? __builtin_amdgcn_readfirstlane(cnt[nB]) : 0;
        const int cA  = min(cFA, CAP);
        const int cB  = min(cFB, CAP);

        int eA = 0, srcA = 0, eB = 0, srcB = 0;
        if (lane < cA) {
            const vi2 p = __builtin_nontemporal_load(
                (const vi2*)buckets + (size_t)nA * CAP + lane);
            eA = p.x; srcA = p.y;
        }
        if (lane < cB) {
            const vi2 p = __builtin_nontemporal_load(
                (const vi2*)buckets + (size_t)nB * CAP + lane);
            eB = p.x; srcB = p.y;
        }

        vf4 axA = {0,0,0,0}, aeA = {0,0,0,0};
        vf4 axB = {0,0,0,0}, aeB = {0,0,0,0};

        const int mMax = max(cA, cB);
        for (int j = 0; j < mMax; j += 16) {
            const int jx0 = j +  0 + grpx, jx1 = j +  4 + grpx;
            const int jx2 = j +  8 + grpx, jx3 = j + 12 + grpx;
            const int je0 = j +  0 + grpe, je1 = j +  8 + grpe;
            // max shuffled lane index 47 < 64; lanes >= cnt hold 0 -> valid.
            const int sA0 = __shfl(srcA, jx0), sA1 = __shfl(srcA, jx1);
            const int sA2 = __shfl(srcA, jx2), sA3 = __shfl(srcA, jx3);
            const int sB0 = __shfl(srcB, jx0), sB1 = __shfl(srcB, jx1);
            const int sB2 = __shfl(srcB, jx2), sB3 = __shfl(srcB, jx3);
            const int fA0 = __shfl(eA, je0),   fA1 = __shfl(eA, je1);
            const int fB0 = __shfl(eB, je0),   fB1 = __shfl(eB, je1);

            vf4 xA0 = {0,0,0,0}, xA1 = {0,0,0,0}, xA2 = {0,0,0,0}, xA3 = {0,0,0,0};
            vf4 xB0 = {0,0,0,0}, xB1 = {0,0,0,0}, xB2 = {0,0,0,0}, xB3 = {0,0,0,0};
            vf4 eA0v = {0,0,0,0}, eA1v = {0,0,0,0};
            vf4 eB0v = {0,0,0,0}, eB1v = {0,0,0,0};

            // all 12 loads issue before any accumulate (independent temps)
            if (jx0 < cA) xA0 = ((const vf4*)(x + (size_t)sA0 * IN_DIM))[colx];
            if (jx1 < cA) xA1 = ((const vf4*)(x + (size_t)sA1 * IN_DIM))[colx];
            if (jx2 < cA) xA2 = ((const vf4*)(x + (size_t)sA2 * IN_DIM))[colx];
            if (jx3 < cA) xA3 = ((const vf4*)(x + (size_t)sA3 * IN_DIM))[colx];
            if (jx0 < cB) xB0 = ((const vf4*)(x + (size_t)sB0 * IN_DIM))[colx];
            if (jx1 < cB) xB1 = ((const vf4*)(x + (size_t)sB1 * IN_DIM))[colx];
            if (jx2 < cB) xB2 = ((const vf4*)(x + (size_t)sB2 * IN_DIM))[colx];
            if (jx3 < cB) xB3 = ((const vf4*)(x + (size_t)sB3 * IN_DIM))[colx];
            if (je0 < cA) eA0v = __builtin_nontemporal_load(
                (const vf4*)(ea + (size_t)fA0 * EDGE_DIM) + cole);
            if (je1 < cA) eA1v = __builtin_nontemporal_load(
                (const vf4*)(ea + (size_t)fA1 * EDGE_DIM) + cole);
            if (je0 < cB) eB0v = __builtin_nontemporal_load(
                (const vf4*)(ea + (size_t)fB0 * EDGE_DIM) + cole);
            if (je1 < cB) eB1v = __builtin_nontemporal_load(
                (const vf4*)(ea + (size_t)fB1 * EDGE_DIM) + cole);

            axA += (xA0 + xA1) + (xA2 + xA3);
            axB += (xB0 + xB1) + (xB2 + xB3);
            aeA += eA0v + eA1v;
            aeB += eB0v + eB1v;
        }

        // rare: overflow entries (deg > CAP). Group 0 accumulates pre-reduce.
        if (cFA > CAP || cFB > CAP) {
            const int novf = min(__builtin_amdgcn_readfirstlane(*ovf_cur), OVF_CAP);
            for (int i = 0; i < novf; ++i) {
                const int4 v = ovf[i];
                const bool mA = (v.x == nA), mB = hasB && (v.x == nB);
                if (mA || mB) {
                    if (grpx == 0) {
                        const vf4 t = ((const vf4*)(x + (size_t)v.z * IN_DIM))[colx];
                        if (mA) axA += t; else axB += t;
                    }
                    if (grpe == 0) {
                        const vf4 t = ((const vf4*)(ea + (size_t)v.y * EDGE_DIM))[cole];
                        if (mA) aeA += t; else aeB += t;
                    }
                }
            }
        }

#pragma unroll
        for (int mask = 16; mask < 64; mask <<= 1) {
            axA.x += __shfl_xor(axA.x, mask); axA.y += __shfl_xor(axA.y, mask);
            axA.z += __shfl_xor(axA.z, mask); axA.w += __shfl_xor(axA.w, mask);
            axB.x += __shfl_xor(axB.x, mask); axB.y += __shfl_xor(axB.y, mask);
            axB.z += __shfl_xor(axB.z, mask); axB.w += __shfl_xor(axB.w, mask);
        }
#pragma unroll
        for (int mask = 8; mask < 64; mask <<= 1) {
            aeA.x += __shfl_xor(aeA.x, mask); aeA.y += __shfl_xor(aeA.y, mask);
            aeA.z += __shfl_xor(aeA.z, mask); aeA.w += __shfl_xor(aeA.w, mask);
            aeB.x += __shfl_xor(aeB.x, mask); aeB.y += __shfl_xor(aeB.y, mask);
            aeB.z += __shfl_xor(aeB.z, mask); aeB.w += __shfl_xor(aeB.w, mask);
        }

        if (lane < 16) ((vf4*)(sum_x + (size_t)nA * IN_DIM))[lane] = axA;
        if (lane < 8)  ((vf4*)(sum_ea + (size_t)nA * EDGE_DIM))[lane] = aeA;
        if (hasB) {
            if (lane < 16) ((vf4*)(sum_x + (size_t)nB * IN_DIM))[lane] = axB;
            if (lane < 8)  ((vf4*)(sum_ea + (size_t)nB * EDGE_DIM))[lane] = aeB;
        }
    }
}

// ---------------------------------------------------------------------------
// K3 (R12): finalize_v5 — lane = NODE, weight = SGPR operand.
// Wave = 64 nodes x 32 output columns (c-half per wave -> 1564 waves, acc[32]).
// Per k: lane's own row component (VGPR) x uniform W[k][c] (SGPR) -> v_fmac.
// 160 FMA/node total across the 2 c-half waves; zero broadcasts, zero LDS.
// Row loads are per-lane 16B (uncoalesced but 4 vf4 share each 64B line -> L1).
// ---------------------------------------------------------------------------
__global__ __launch_bounds__(256) void finalize_v5_k(
    const float* __restrict__ x, const float* __restrict__ sum_x_in,
    const float* __restrict__ sum_ea, const int* __restrict__ cnt,
    const float* __restrict__ msg_w, const float* __restrict__ msg_b,
    const float* __restrict__ self_w, const float* __restrict__ self_b,
    float* __restrict__ out)
{
    const int lane   = threadIdx.x & 63;
    const int wunit  = blockIdx.x * 4 + (threadIdx.x >> 6);  // 0..1563
    const int rowblk = wunit >> 1;                            // 0..781
    const int c0     = (wunit & 1) << 5;                      // 0 or 32
    const int n      = rowblk * 64 + lane;
    const bool live  = (n < N_NODES);
    const int  nn    = live ? n : 0;   // clamp: safe loads, store masked

    const vf4* rx = (const vf4*)(sum_x_in + (size_t)nn * IN_DIM);
    const vf4* re = (const vf4*)(sum_ea   + (size_t)nn * EDGE_DIM);
    const vf4* rs = (const vf4*)(x        + (size_t)nn * IN_DIM);
    const int  d  = cnt[nn];

    float acc[32];
#pragma unroll
    for (int c = 0; c < 32; ++c) acc[c] = 0.f;

    // message part, k = 0..63 (sum_x)
#pragma unroll 2
    for (int q = 0; q < 16; ++q) {
        const vf4 v  = rx[q];
        const int kb = __builtin_amdgcn_readfirstlane(4 * q);  // force SGPR
#pragma unroll
        for (int i = 0; i < 4; ++i) {
            const float  vi   = v[i];
            const float* wrow = msg_w + (size_t)(kb + i) * OUT_DIM + c0;
#pragma unroll
            for (int c = 0; c < 32; ++c)
                acc[c] = fmaf(vi, wrow[c], acc[c]);   // wrow[c] uniform -> SGPR
        }
    }
    // message part, k = 64..95 (sum_ea)
#pragma unroll 2
    for (int q = 0; q < 8; ++q) {
        const vf4 v  = re[q];
        const int kb = __builtin_amdgcn_readfirstlane(64 + 4 * q);
#pragma unroll
        for (int i = 0; i < 4; ++i) {
            const float  vi   = v[i];
            const float* wrow = msg_w + (size_t)(kb + i) * OUT_DIM + c0;
#pragma unroll
            for (int c = 0; c < 32; ++c)
                acc[c] = fmaf(vi, wrow[c], acc[c]);
        }
    }

    // mean + msg bias (bias only when deg>0)
    const float inv  = 1.0f / (float)max(d, 1);
    const float bsel = (d > 0) ? 1.0f : 0.0f;
#pragma unroll
    for (int c = 0; c < 32; ++c)
        acc[c] = fmaf(acc[c], inv, msg_b[c0 + c] * bsel);

    // self part, k = 0..63 (x)
#pragma unroll 2
    for (int q = 0; q < 16; ++q) {
        const vf4 v  = rs[q];
        const int kb = __builtin_amdgcn_readfirstlane(4 * q);
#pragma unroll
        for (int i = 0; i < 4; ++i) {
            const float  vi   = v[i];
            const float* wrow = self_w + (size_t)(kb + i) * OUT_DIM + c0;
#pragma unroll
            for (int c = 0; c < 32; ++c)
                acc[c] = fmaf(vi, wrow[c], acc[c]);
        }
    }
#pragma unroll
    for (int c = 0; c < 32; ++c) acc[c] += self_b[c0 + c];

    if (live) {
        float* op = out + (size_t)n * OUT_DIM + c0;
#pragma unroll
        for (int qq = 0; qq < 8; ++qq)
            ((vf4*)op)[qq] = (vf4){acc[4 * qq + 0], acc[4 * qq + 1],
                                   acc[4 * qq + 2], acc[4 * qq + 3]};
    }
}

// ---------------------------------------------------------------------------
// Tier-3 fallback: atomic scatter (needs only ~19.4 MB ws).
// ---------------------------------------------------------------------------
__global__ __launch_bounds__(768) void scatter_fb_k(
    const float* __restrict__ x, const int* __restrict__ ei,
    const float* __restrict__ ea, float* sum_x, float* sum_ea, int* deg)
{
    const int t  = threadIdx.x;
    const int el = t / 96;
    const int k  = t - el * 96;
    const int e  = blockIdx.x * 8 + el;
    if (e >= N_EDGES) return;
    const int dst = ei[N_EDGES + e];
    if (k < IN_DIM) {
        const int src = ei[e];
        atomicAdd(&sum_x[dst * IN_DIM + k], x[src * IN_DIM + k]);
        if (k == 0) atomicAdd(&deg[dst], 1);
    } else {
        const int kk = k - IN_DIM;
        atomicAdd(&sum_ea[dst * EDGE_DIM + kk], ea[e * EDGE_DIM + kk]);
    }
}

// ---------------------------------------------------------------------------
extern "C" void kernel_launch(void* const* d_in, const int* in_sizes, int n_in,
                              void* d_out, int out_size, void* d_ws, size_t ws_size,
                              hipStream_t stream) {
    const float* x      = (const float*)d_in[0];
    const int*   ei     = (const int*)d_in[1];   // [2][E]
    const float* ea     = (const float*)d_in[2];
    const float* msg_w  = (const float*)d_in[3];
    const float* msg_b  = (const float*)d_in[4];
    const float* self_w = (const float*)d_in[5];
    const float* self_b = (const float*)d_in[6];

    float* out = (float*)d_out;

    // ws layout (ints unless noted):
    //   cnt[50000] | ovf_cur[1] | pad to 16 | buckets[50000*CAP int2]
    //   | ovf[OVF_CAP int4] | sum_ea[1.6M float] | sum_x[3.2M float]
    int*   cnt     = (int*)d_ws;
    int*   ovf_cur = cnt + N_NODES;
    int2*  buckets = (int2*)(cnt + N_NODES + 16);
    int4*  ovf     = (int4*)(buckets + (size_t)N_NODES * CAP);
    float* sum_ea  = (float*)(ovf + OVF_CAP);
    float* sum_x   = sum_ea + (size_t)N_NODES * EDGE_DIM;
    const size_t need_bucket =
        ((size_t)N_NODES + 16 + 2 * (size_t)N_NODES * CAP + 4 * (size_t)OVF_CAP +
         (size_t)N_NODES * EDGE_DIM + (size_t)N_NODES * IN_DIM) * sizeof(int);

    constexpr int FIN_BLOCKS = ((N_NODES + 63) / 64 * 2 + 3) / 4;  // 391

    if (ws_size >= need_bucket) {
        hipMemsetAsync(cnt, 0, (N_NODES + 16) * sizeof(int), stream);
        place_bucket_k<<<(N_EDGES / 4 + 255) / 256, 256, 0, stream>>>(
            ei, cnt, buckets, ovf, ovf_cur);
        aggregate_bucket_k<<<(N_NODES / 2 + 3) / 4, 256, 0, stream>>>(
            x, ea, buckets, cnt, ovf, ovf_cur, sum_x, sum_ea);
        finalize_v5_k<<<FIN_BLOCKS, 256, 0, stream>>>(
            x, sum_x, sum_ea, cnt, msg_w, msg_b, self_w, self_b, out);
    } else {
        // Fallback: fp32 atomic scatter (R1 path) + finalize_v5
        float* fb_sum_x  = (float*)d_ws;
        float* fb_sum_ea = fb_sum_x + (size_t)N_NODES * IN_DIM;
        int*   deg       = (int*)(fb_sum_ea + (size_t)N_NODES * EDGE_DIM);
        hipMemsetAsync(d_ws, 0,
                       (size_t)N_NODES * (IN_DIM + EDGE_DIM + 1) * sizeof(float),
                       stream);
        scatter_fb_k<<<(N_EDGES + 7) / 8, 768, 0, stream>>>(
            x, ei, ea, fb_sum_x, fb_sum_ea, deg);
        finalize_v5_k<<<FIN_BLOCKS, 256, 0, stream>>>(
            x, fb_sum_x, fb_sum_ea, deg, msg_w, msg_b, self_w, self_b, out);
    }
}